// Round 5
// baseline (31.002 us; speedup 1.0000x reference)
//
#include <hip/hip_runtime.h>
#include <math.h>

#define NPTS 2048
#define KDIM 400
#define NBLK 256
#define NFF  128          // blocks 0..127: FF producers; 128..255: kval+field

__device__ unsigned bar_g;   // .bss -> 0 at module load; +NBLK per launch, stays aligned

__global__ __launch_bounds__(512) void k_fused(
    const float* __restrict__ weights, const float* __restrict__ grid,
    const float* __restrict__ ff_w1, const float* __restrict__ ff_b1,
    const float* __restrict__ ff_w2, const float* __restrict__ ff_b2,
    const float* __restrict__ ff_w3, const float* __restrict__ ff_b3,
    const float* __restrict__ k_w1, const float* __restrict__ k_b1,
    const float* __restrict__ k_w2, const float* __restrict__ k_b2,
    const float* __restrict__ k_w3, const float* __restrict__ k_b3,
    float* __restrict__ integ, float2* __restrict__ out)
{
    // FF blocks use 1976 floats; kval blocks: weights 1002 + kv/kidx 768 + Li 12800
    __shared__ float S[14592];   // 58368 B -> 2 blocks/CU schedulable (no deadlock)
    const int t = threadIdx.x;
    const int bid = blockIdx.x;

    if (bid < NFF) {
        // ---------- FF producer: block pair (b, half), split-K layers ----------
        const int b = bid >> 1, half = bid & 1;
        float* wrow = S;         // 256
        float* h1   = S + 256;   // 120
        float* h2   = S + 376;   // 240
        float* p1   = S + 616;   // 4*120
        float* p2   = S + 1096;  // 2*240
        float* p3   = S + 1576;  // 2*200

        if (t < 256) wrow[t] = weights[b * 256 + t];
        __syncthreads();

        if (t < 480) {           // layer 1: 120 outs, 4-way split-K (64 each)
            const int seg = t / 120, o = t - seg * 120;
            float s = (seg == 0) ? ff_b1[o] : 0.f;
            const int i0 = seg * 64;
            #pragma unroll 16
            for (int i = 0; i < 64; ++i)
                s = fmaf(wrow[i0 + i], ff_w1[(i0 + i) * 120 + o], s);
            p1[seg * 120 + o] = s;
        }
        __syncthreads();
        if (t < 120) h1[t] = tanhf(p1[t] + p1[120 + t] + p1[240 + t] + p1[360 + t]);
        __syncthreads();

        if (t < 480) {           // layer 2: 240 outs, 2-way split-K (60 each)
            const int seg = t / 240, o = t - seg * 240;
            float s = (seg == 0) ? ff_b2[o] : 0.f;
            const int i0 = seg * 60;
            #pragma unroll 15
            for (int i = 0; i < 60; ++i)
                s = fmaf(h1[i0 + i], ff_w2[(i0 + i) * 240 + o], s);
            p2[seg * 240 + o] = s;
        }
        __syncthreads();
        if (t < 240) h2[t] = tanhf(p2[t] + p2[240 + t]);
        __syncthreads();

        if (t < 400) {           // layer 3: this block's 200 outs, 2-way split-K
            const int seg = t / 200, o = t - seg * 200, oc = half * 200 + o;
            float s = (seg == 0) ? ff_b3[oc] : 0.f;
            const int i0 = seg * 120;
            #pragma unroll 15
            for (int i = 0; i < 120; ++i)
                s = fmaf(h2[i0 + i], ff_w3[(i0 + i) * 400 + oc], s);
            p3[seg * 200 + o] = s;
        }
        __syncthreads();
        if (t < 200)             // agent-coherent store: write-through past XCD L2
            __hip_atomic_store(&integ[b * 400 + half * 200 + t], p3[t] + p3[200 + t],
                               __ATOMIC_RELAXED, __HIP_MEMORY_SCOPE_AGENT);
        __syncthreads();         // every wave drains vmcnt before t0 can pass
        if (t == 0)
            __hip_atomic_fetch_add(&bar_g, 1u, __ATOMIC_RELAXED, __HIP_MEMORY_SCOPE_AGENT);
        return;                  // producers exit; no spin
    }

    // ---------- kval + field block: 16 points, kv kept in LDS ----------
    float* sw1 = S;              // 80
    float* sb1 = S + 80;         // 40
    float* sw2 = S + 120;        // 800
    float* sb2 = S + 920;        // 40
    float* sw3 = S + 960;        // 40
    float* sb3 = S + 1000;       // 2
    float* kvs = S + 1024;       // [2][16][16] (f, slot, pt)
    int*   kidxs = (int*)(S + 1536); // [16][16] (slot, pt)
    float* Li  = S + 1792;       // [32][400] integ stage (one half per pass)

    for (int i = t; i < 80;  i += 512) sw1[i] = k_w1[i];
    for (int i = t; i < 800; i += 512) sw2[i] = k_w2[i];
    if (t < 40) { sb1[t] = k_b1[t]; sb2[t] = k_b2[t]; sw3[t] = k_w3[t]; }
    if (t < 2)  sb3[t] = k_b3[t];
    __syncthreads();

    const int pid  = bid - NFF;        // 0..127, 16 points each
    const int f    = t >> 8;           // 0/1
    const int idx  = t & 255;
    const int slot = idx >> 4;         // 0..15 -> 4x4 window
    const int pt   = idx & 15;
    const int n    = pid * 16 + pt;
    const float2 g2 = ((const float2*)grid)[n];
    const float x = g2.x, y = g2.y;
    const int ilx = (int)ceilf((x - 0.15f) * 20.0f - 0.01f);
    const int ily = (int)ceilf((y - 0.15f) * 20.0f - 0.01f);
    const int ix = ilx + (slot >> 2);
    const int iy = ily + (slot & 3);

    float kv = 0.f;
    int k = 0;
    if (ix >= 0 && ix < 20 && iy >= 0 && iy < 20) {
        // replicate reference f32 arithmetic exactly (no fp-contract)
        const float gx = __fmul_rn((float)ix, 0.05f);
        const float gy = __fmul_rn((float)iy, 0.05f);
        const float lx = __fsub_rn(x, gx);
        const float ly = __fsub_rn(y, gy);
        if (lx >= 0.f && lx <= 0.15f && ly >= 0.f && ly <= 0.15f) {
            k = ix * 20 + iy;
            float hv[20];
            #pragma unroll
            for (int hh = 0; hh < 20; ++hh)
                hv[hh] = fmaxf(0.f,
                    fmaf(lx, sw1[f * 40 + hh],
                    fmaf(ly, sw1[f * 40 + 20 + hh], sb1[f * 20 + hh])));
            float o = sb3[f];
            #pragma unroll
            for (int g = 0; g < 20; ++g) {
                float s = sb2[f * 20 + g];
                #pragma unroll
                for (int hh = 0; hh < 20; ++hh)
                    s = fmaf(hv[hh], sw2[f * 400 + hh * 20 + g], s);
                o = fmaf(fmaxf(0.f, s), sw3[f * 20 + g], o);
            }
            kv = o;
        }
    }
    kvs[f * 256 + slot * 16 + pt] = kv;
    if (f == 0) kidxs[slot * 16 + pt] = k;   // k=0 with kv=0 is harmless
    __syncthreads();

    // ---- init-free monotonic ticket barrier (no fences, no memset) ----
    if (t == 0) {
        const unsigned r = __hip_atomic_fetch_add(&bar_g, 1u, __ATOMIC_RELAXED,
                                                  __HIP_MEMORY_SCOPE_AGENT);
        const unsigned target = (r & ~(unsigned)(NBLK - 1)) + (unsigned)NBLK;
        while ((int)(__hip_atomic_load(&bar_g, __ATOMIC_RELAXED,
                                       __HIP_MEMORY_SCOPE_AGENT) - target) < 0)
            __builtin_amdgcn_s_sleep(4);
    }
    __syncthreads();

    // ---- phase 2: this block's 16 points x all 64 b, two 32-row passes ----
    #pragma unroll 1
    for (int pass = 0; pass < 2; ++pass) {
        const float* src = integ + pass * 32 * KDIM;
        for (int i = t; i < 32 * KDIM; i += 512)   // agent loads bypass stale L1/L2
            Li[i] = __hip_atomic_load(src + i, __ATOMIC_RELAXED,
                                      __HIP_MEMORY_SCOPE_AGENT);
        __syncthreads();

        const int bl = t >> 4;          // 0..31 local batch row
        const int pp = t & 15;          // point within block
        float a0 = 0.f, a1 = 0.f;
        #pragma unroll
        for (int j = 0; j < 16; ++j) {
            const float w = Li[bl * KDIM + kidxs[j * 16 + pp]];
            a0 = fmaf(kvs[j * 16 + pp], w, a0);
            a1 = fmaf(kvs[256 + j * 16 + pp], w, a1);
        }
        out[(pass * 32 + bl) * NPTS + pid * 16 + pp] =
            make_float2(1.f / (1.f + __expf(-a0)), 1.f / (1.f + __expf(-a1)));
        __syncthreads();                // protect Li before next pass overwrites
    }
}

extern "C" void kernel_launch(void* const* d_in, const int* in_sizes, int n_in,
                              void* d_out, int out_size, void* d_ws, size_t ws_size,
                              hipStream_t stream) {
    const float* weights = (const float*)d_in[0];
    const float* grid    = (const float*)d_in[1];
    const float* ff_w1   = (const float*)d_in[2];
    const float* ff_b1   = (const float*)d_in[3];
    const float* ff_w2   = (const float*)d_in[4];
    const float* ff_b2   = (const float*)d_in[5];
    const float* ff_w3   = (const float*)d_in[6];
    const float* ff_b3   = (const float*)d_in[7];
    const float* k_w1    = (const float*)d_in[8];
    const float* k_b1    = (const float*)d_in[9];
    const float* k_w2    = (const float*)d_in[10];
    const float* k_b2    = (const float*)d_in[11];
    const float* k_w3    = (const float*)d_in[12];
    const float* k_b3    = (const float*)d_in[13];

    float* integ = (float*)d_ws;                 // 64*400 floats

    k_fused<<<NBLK, 512, 0, stream>>>(
        weights, grid, ff_w1, ff_b1, ff_w2, ff_b2, ff_w3, ff_b3,
        k_w1, k_b1, k_w2, k_b2, k_w3, k_b3,
        integ, (float2*)d_out);
}

// Round 6
// 19.115 us; speedup vs baseline: 1.6219x; 1.6219x over previous
//
#include <hip/hip_runtime.h>
#include <math.h>

#define NPTS 2048
#define KDIM 400
#define NBLK 256
#define NFF  128          // blocks 0..127: FF producers; 128..255: kval+field

typedef float f32x4 __attribute__((ext_vector_type(4)));

__device__ unsigned bar_g;   // .bss -> 0 at load; +NBLK per launch, stays aligned

// 16B device-coherent load (bypasses L1/L2 like agent-scope atomic, but wide).
__device__ __forceinline__ f32x4 load_coherent16(const void* p) {
    f32x4 r;
    asm volatile("global_load_dwordx4 %0, %1, off sc0 sc1"
                 : "=&v"(r) : "v"(p) : "memory");
    return r;
}

__global__ __launch_bounds__(512) void k_fused(
    const float* __restrict__ weights, const float* __restrict__ grid,
    const float* __restrict__ ff_w1, const float* __restrict__ ff_b1,
    const float* __restrict__ ff_w2, const float* __restrict__ ff_b2,
    const float* __restrict__ ff_w3, const float* __restrict__ ff_b3,
    const float* __restrict__ k_w1, const float* __restrict__ k_b1,
    const float* __restrict__ k_w2, const float* __restrict__ k_b2,
    const float* __restrict__ k_w3, const float* __restrict__ k_b3,
    float* __restrict__ integ, float2* __restrict__ out)
{
    // FF blocks: 1976 floats. kval blocks: weights 1024 + kv/kidx 768 + Li 25600.
    __shared__ __align__(16) float S[27392];   // 109.6 KB; grid==CU count -> 1 blk/CU
    const int t = threadIdx.x;
    const int bid = blockIdx.x;

    if (bid < NFF) {
        // ---------- FF producer: block pair (b, half), split-K layers ----------
        const int b = bid >> 1, half = bid & 1;
        float* wrow = S;         // 256
        float* h1   = S + 256;   // 120
        float* h2   = S + 376;   // 240
        float* p1   = S + 616;   // 4*120
        float* p2   = S + 1096;  // 2*240
        float* p3   = S + 1576;  // 2*200

        if (t < 256) wrow[t] = weights[b * 256 + t];
        __syncthreads();

        if (t < 480) {           // layer 1: 120 outs, 4-way split-K (64 each)
            const int seg = t / 120, o = t - seg * 120;
            float s = (seg == 0) ? ff_b1[o] : 0.f;
            const int i0 = seg * 64;
            #pragma unroll 16
            for (int i = 0; i < 64; ++i)
                s = fmaf(wrow[i0 + i], ff_w1[(i0 + i) * 120 + o], s);
            p1[seg * 120 + o] = s;
        }
        __syncthreads();
        if (t < 120) h1[t] = tanhf(p1[t] + p1[120 + t] + p1[240 + t] + p1[360 + t]);
        __syncthreads();

        if (t < 480) {           // layer 2: 240 outs, 2-way split-K (60 each)
            const int seg = t / 240, o = t - seg * 240;
            float s = (seg == 0) ? ff_b2[o] : 0.f;
            const int i0 = seg * 60;
            #pragma unroll 15
            for (int i = 0; i < 60; ++i)
                s = fmaf(h1[i0 + i], ff_w2[(i0 + i) * 240 + o], s);
            p2[seg * 240 + o] = s;
        }
        __syncthreads();
        if (t < 240) h2[t] = tanhf(p2[t] + p2[240 + t]);
        __syncthreads();

        if (t < 400) {           // layer 3: this block's 200 outs, 2-way split-K
            const int seg = t / 200, o = t - seg * 200, oc = half * 200 + o;
            float s = (seg == 0) ? ff_b3[oc] : 0.f;
            const int i0 = seg * 120;
            #pragma unroll 15
            for (int i = 0; i < 120; ++i)
                s = fmaf(h2[i0 + i], ff_w3[(i0 + i) * 400 + oc], s);
            p3[seg * 200 + o] = s;
        }
        __syncthreads();
        if (t < 200)             // agent-coherent store: write-through past XCD L2
            __hip_atomic_store(&integ[b * 400 + half * 200 + t], p3[t] + p3[200 + t],
                               __ATOMIC_RELAXED, __HIP_MEMORY_SCOPE_AGENT);
        __syncthreads();         // every wave drains vmcnt before t0 can pass
        if (t == 0)
            __hip_atomic_fetch_add(&bar_g, 1u, __ATOMIC_RELAXED, __HIP_MEMORY_SCOPE_AGENT);
        return;                  // producers exit; no spin
    }

    // ---------- kval + field block: 16 points, kv kept in LDS ----------
    float* sw1 = S;              // 80
    float* sb1 = S + 80;         // 40
    float* sw2 = S + 120;        // 800
    float* sb2 = S + 920;        // 40
    float* sw3 = S + 960;        // 40
    float* sb3 = S + 1000;       // 2
    float* kvs = S + 1024;       // [2][16][16] (f, slot, pt)
    int*   kidxs = (int*)(S + 1536); // [16][16] (slot, pt)
    float* Li  = S + 1792;       // [64][400] full integ stage

    for (int i = t; i < 80;  i += 512) sw1[i] = k_w1[i];
    for (int i = t; i < 800; i += 512) sw2[i] = k_w2[i];
    if (t < 40) { sb1[t] = k_b1[t]; sb2[t] = k_b2[t]; sw3[t] = k_w3[t]; }
    if (t < 2)  sb3[t] = k_b3[t];
    __syncthreads();

    const int pid  = bid - NFF;        // 0..127, 16 points each
    const int f    = t >> 8;           // 0/1
    const int idx  = t & 255;
    const int slot = idx >> 4;         // 0..15 -> 4x4 window
    const int pt   = idx & 15;
    const int n    = pid * 16 + pt;
    const float2 g2 = ((const float2*)grid)[n];
    const float x = g2.x, y = g2.y;
    const int ilx = (int)ceilf((x - 0.15f) * 20.0f - 0.01f);
    const int ily = (int)ceilf((y - 0.15f) * 20.0f - 0.01f);
    const int ix = ilx + (slot >> 2);
    const int iy = ily + (slot & 3);

    float kv = 0.f;
    int k = 0;
    if (ix >= 0 && ix < 20 && iy >= 0 && iy < 20) {
        // replicate reference f32 arithmetic exactly (no fp-contract)
        const float gx = __fmul_rn((float)ix, 0.05f);
        const float gy = __fmul_rn((float)iy, 0.05f);
        const float lx = __fsub_rn(x, gx);
        const float ly = __fsub_rn(y, gy);
        if (lx >= 0.f && lx <= 0.15f && ly >= 0.f && ly <= 0.15f) {
            k = ix * 20 + iy;
            float hv[20];
            #pragma unroll
            for (int hh = 0; hh < 20; ++hh)
                hv[hh] = fmaxf(0.f,
                    fmaf(lx, sw1[f * 40 + hh],
                    fmaf(ly, sw1[f * 40 + 20 + hh], sb1[f * 20 + hh])));
            float o = sb3[f];
            #pragma unroll
            for (int g = 0; g < 20; ++g) {
                float s = sb2[f * 20 + g];
                #pragma unroll
                for (int hh = 0; hh < 20; ++hh)
                    s = fmaf(hv[hh], sw2[f * 400 + hh * 20 + g], s);
                o = fmaf(fmaxf(0.f, s), sw3[f * 20 + g], o);
            }
            kv = o;
        }
    }
    kvs[f * 256 + slot * 16 + pt] = kv;
    if (f == 0) kidxs[slot * 16 + pt] = k;   // k=0 with kv=0 is harmless
    __syncthreads();

    // ---- init-free monotonic ticket barrier (no fences, no memset) ----
    if (t == 0) {
        const unsigned r = __hip_atomic_fetch_add(&bar_g, 1u, __ATOMIC_RELAXED,
                                                  __HIP_MEMORY_SCOPE_AGENT);
        const unsigned target = (r & ~(unsigned)(NBLK - 1)) + (unsigned)NBLK;
        while ((int)(__hip_atomic_load(&bar_g, __ATOMIC_RELAXED,
                                       __HIP_MEMORY_SCOPE_AGENT) - target) < 0)
            __builtin_amdgcn_s_sleep(1);
    }
    __syncthreads();

    // ---- stage ALL of integ (64x400 = 6400 float4) via wide coherent loads ----
    {
        f32x4 tmp[13];
        #pragma unroll
        for (int kk = 0; kk < 13; ++kk) {
            const int i4 = t + kk * 512;
            if (i4 < 6400) tmp[kk] = load_coherent16((const void*)(integ + i4 * 4));
        }
        asm volatile("s_waitcnt vmcnt(0)" ::: "memory");
        __builtin_amdgcn_sched_barrier(0);
        #pragma unroll
        for (int kk = 0; kk < 13; ++kk) {
            const int i4 = t + kk * 512;
            if (i4 < 6400) ((f32x4*)Li)[i4] = tmp[kk];
        }
    }
    __syncthreads();

    // ---- phase 2: this block's 16 points x all 64 batch rows ----
    #pragma unroll
    for (int h = 0; h < 2; ++h) {
        const int q  = t + h * 512;      // 0..1023
        const int b  = q >> 4;           // 0..63
        const int pp = q & 15;
        float a0 = 0.f, a1 = 0.f;
        #pragma unroll
        for (int j = 0; j < 16; ++j) {
            const float w = Li[b * KDIM + kidxs[j * 16 + pp]];
            a0 = fmaf(kvs[j * 16 + pp], w, a0);
            a1 = fmaf(kvs[256 + j * 16 + pp], w, a1);
        }
        out[b * NPTS + pid * 16 + pp] =
            make_float2(1.f / (1.f + __expf(-a0)), 1.f / (1.f + __expf(-a1)));
    }
}

extern "C" void kernel_launch(void* const* d_in, const int* in_sizes, int n_in,
                              void* d_out, int out_size, void* d_ws, size_t ws_size,
                              hipStream_t stream) {
    const float* weights = (const float*)d_in[0];
    const float* grid    = (const float*)d_in[1];
    const float* ff_w1   = (const float*)d_in[2];
    const float* ff_b1   = (const float*)d_in[3];
    const float* ff_w2   = (const float*)d_in[4];
    const float* ff_b2   = (const float*)d_in[5];
    const float* ff_w3   = (const float*)d_in[6];
    const float* ff_b3   = (const float*)d_in[7];
    const float* k_w1    = (const float*)d_in[8];
    const float* k_b1    = (const float*)d_in[9];
    const float* k_w2    = (const float*)d_in[10];
    const float* k_b2    = (const float*)d_in[11];
    const float* k_w3    = (const float*)d_in[12];
    const float* k_b3    = (const float*)d_in[13];

    float* integ = (float*)d_ws;                 // 64*400 floats

    k_fused<<<NBLK, 512, 0, stream>>>(
        weights, grid, ff_w1, ff_b1, ff_w2, ff_b2, ff_w3, ff_b3,
        k_w1, k_b1, k_w2, k_b2, k_w3, k_b3,
        integ, (float2*)d_out);
}